// Round 8
// baseline (151.015 us; speedup 1.0000x reference)
//
#include <hip/hip_runtime.h>
#include <math.h>

#define QN 12
#define QDIM 4096
#define CHEB_TOL 2e-3f
// Swizzled LDS index (float2 units): pad 2 float2 per 16 -> uniform bank use.
// L(g) = g + 2*(g>>4). Quad g0..g0+3 stays contiguous & 16B-aligned.
#define LSZ (QDIM + 2 * (QDIM / 16))

// DPP lane permutations on the VALU pipe (no LDS traffic). All involutions;
// HW-verified in rounds 4/5/7.
template <int CTRL>
__device__ __forceinline__ float dppf(float x) {
    int v = __builtin_amdgcn_update_dpp(0, __float_as_int(x), CTRL, 0xF, 0xF, false);
    return __int_as_float(v);
}
#define DPP_QX1 0xB1   // quad_perm [1,0,3,2]  : lane ^ 1
#define DPP_QX2 0x4E   // quad_perm [2,3,0,1]  : lane ^ 2
#define DPP_QX3 0x1B   // quad_perm [3,2,1,0]  : lane ^ 3
#define DPP_HM  0x141  // row_half_mirror      : lane ^ 7
#define DPP_R8  0x128  // row_ror:8            : lane ^ 8
__device__ __forceinline__ float dpp_x1(float x) { return dppf<DPP_QX1>(x); }
__device__ __forceinline__ float dpp_x2(float x) { return dppf<DPP_QX2>(x); }
__device__ __forceinline__ float dpp_x4(float x) { return dppf<DPP_HM>(dppf<DPP_QX3>(x)); }
__device__ __forceinline__ float dpp_x8(float x) { return dppf<DPP_R8>(x); }

// gfx950 permlane swaps via clang builtins (NOT inline asm — R6 showed tied-
// operand asm causes scratch spills; the builtin returns both outputs as a
// value pair so the allocator stays in control). Sum identity is convention-
// proof: after swap(a=x, b=x), a+b == x + x^16 (resp. x^32) at every lane.
#if defined(__has_builtin)
#  if __has_builtin(__builtin_amdgcn_permlane16_swap) && __has_builtin(__builtin_amdgcn_permlane32_swap)
#    define HAVE_PERMLANE_SWAP 1
#  endif
#endif
#ifndef HAVE_PERMLANE_SWAP
#  define HAVE_PERMLANE_SWAP 0
#endif

#if HAVE_PERMLANE_SWAP
__device__ __forceinline__ float xor16_sum(float x) {
    auto r = __builtin_amdgcn_permlane16_swap(__float_as_uint(x), __float_as_uint(x), false, false);
    return __uint_as_float(r[0]) + __uint_as_float(r[1]);   // = x + x^16
}
__device__ __forceinline__ float xor32_sum(float x) {
    auto r = __builtin_amdgcn_permlane32_swap(__float_as_uint(x), __float_as_uint(x), false, false);
    return __uint_as_float(r[0]) + __uint_as_float(r[1]);   // = x + x^32
}
#define JLDS_START 8   // bits 6,7 handled on the VALU pipe
#else
#define JLDS_START 6   // fallback: bits 6,7 via LDS (round-7 behavior)
#endif

// Stage 1: psi_t = exp(-i t H)|init> via Chebyshev, one block per t.
// 1024 threads x 4 consecutive elements. Couplings: element bits 0,1 from
// registers; bits 2..5 via DPP; bits 6,7 via permlane swap (if available);
// remaining bits via swizzled LDS ping-pong.
__global__ __launch_bounds__(1024) void evolve_kernel(
    const int* __restrict__ init_state,
    const float* __restrict__ ts,
    const float* __restrict__ params_x,
    const float* __restrict__ params_zz,
    float2* __restrict__ psi_out)
{
    __shared__ float2 bufA[LSZ];
    __shared__ float2 bufB[LSZ];
    __shared__ float  Jc[128];
    __shared__ float  suLDS[160];
    __shared__ int    dsh;

    const int tid = threadIdx.x;
    const int tI  = blockIdx.x;
    const float t = ts[tI];
    const int g0 = tid * 4;
    const int h0 = g0 >> 4;           // = tid >> 2
    const int l0 = g0 + 2 * h0;       // swizzled base for own quad

    if (tid < 160) suLDS[tid] = 0.f;

    float xj[QN];
    float bound = 0.f;
#pragma unroll
    for (int j = 0; j < QN; ++j) { xj[j] = params_x[j]; bound += fabsf(xj[j]); }
    float zz[QN - 1];
#pragma unroll
    for (int i = 0; i < QN - 1; ++i) { zz[i] = params_zz[i]; bound += fabsf(zz[i]); }

    // diagonal (ZZ) term for the 4 owned elements
    float dg[4];
#pragma unroll
    for (int k = 0; k < 4; ++k) {
        const int g = g0 + k;
        float dv = 0.f;
#pragma unroll
        for (int i = 0; i < QN - 1; ++i) {
            const int flip = ((g >> i) ^ (g >> (i + 1))) & 1;
            dv += zz[i] * (1.0f - 2.0f * (float)flip);
        }
        dg[k] = dv;
    }

    const float theta = t * bound;
    int dmax = (int)ceilf(theta + 5.0f * cbrtf(theta)) + 6;
    if (dmax < 8) dmax = 8;
    if (dmax > 126) dmax = 126;

    // Bessel J_k(theta) via Miller backward recurrence (fp64, rolling).
    {
        const int M = dmax + 24;
        const double th = (double)fmaxf(theta, 1e-6f);
        const double invth = 1.0 / th;
        double jkp1 = 0.0, jk = 1e-30, mine = 0.0, nrm = 0.0, suf = 0.0, su_own = 0.0;
        for (int k = M; k >= 0; --k) {
            suf += fabs(jk);
            if (k == tid) { mine = jk; su_own = suf; }
            if (k == 0) nrm += jk;
            else if ((k & 1) == 0) nrm += 2.0 * jk;
            const double jkm1 = (2.0 * (double)k * invth) * jk - jkp1;
            jkp1 = jk; jk = jkm1;
            if (fabs(jk) > 1e250) {
                jk *= 1e-250; jkp1 *= 1e-250; mine *= 1e-250;
                nrm *= 1e-250; suf *= 1e-250; su_own *= 1e-250;
            }
        }
        const double anrm = fabs(nrm);
        if (tid <= dmax) Jc[tid] = (float)(mine / nrm);
        if (tid < 160) suLDS[tid] = (float)(su_own / anrm);
    }

    const int is = init_state[0];
    const float inv_s = 1.0f / bound;

    float2 tp[4];    // T_{k-1}
    float2 tpp[4];   // T_{k-2}
    float2 acc[4];
#pragma unroll
    for (int k = 0; k < 4; ++k) {
        const float v = (g0 + k == is) ? 1.0f : 0.0f;
        tp[k]  = make_float2(v, 0.f);
        tpp[k] = make_float2(0.f, 0.f);
        bufA[l0 + k] = tp[k];
    }
    __syncthreads();   // Jc/suLDS/bufA visible

    // adaptive degree: smallest d with suffix(d+1) < tol (wave-0 double ballot)
    if (tid < 64) {
        const bool p0 = suLDS[tid + 1] < CHEB_TOL;
        const bool p1 = suLDS[tid + 65] < CHEB_TOL;
        const unsigned long long b0 = __ballot(p0);
        const unsigned long long b1 = __ballot(p1);
        if (tid == 0) {
            int dd;
            if (b0) dd = __ffsll(b0) - 1;
            else if (b1) dd = 64 + __ffsll(b1) - 1;
            else dd = dmax;
            if (dd < 2) dd = 2;
            if (dd > dmax) dd = dmax;
            dsh = dd;
        }
    }
    __syncthreads();
    const int d = dsh;

#pragma unroll
    for (int k = 0; k < 4; ++k) {
        acc[k] = make_float2(Jc[0] * tp[k].x, 0.f);
    }

    float2* cur = bufA;
    float2* nxt = bufB;

    for (int k = 1; k <= d; ++k) {
        float hr[4], hi[4];
#pragma unroll
        for (int kk = 0; kk < 4; ++kk) {
            // element bits 0,1: register neighbors
            hr[kk] = dg[kk] * tp[kk].x + xj[0] * tp[kk ^ 1].x + xj[1] * tp[kk ^ 2].x;
            hi[kk] = dg[kk] * tp[kk].y + xj[0] * tp[kk ^ 1].y + xj[1] * tp[kk ^ 2].y;
            // element bits 2..5: DPP lane-xor 1,2,4,8 (VALU pipe)
            hr[kk] += xj[2] * dpp_x1(tp[kk].x);
            hi[kk] += xj[2] * dpp_x1(tp[kk].y);
            hr[kk] += xj[3] * dpp_x2(tp[kk].x);
            hi[kk] += xj[3] * dpp_x2(tp[kk].y);
            hr[kk] += xj[4] * dpp_x4(tp[kk].x);
            hi[kk] += xj[4] * dpp_x4(tp[kk].y);
            hr[kk] += xj[5] * dpp_x8(tp[kk].x);
            hi[kk] += xj[5] * dpp_x8(tp[kk].y);
#if HAVE_PERMLANE_SWAP
            // element bits 6,7: permlane16/32 swap (VALU pipe), x^m = sum - x
            hr[kk] += xj[6] * (xor16_sum(tp[kk].x) - tp[kk].x);
            hi[kk] += xj[6] * (xor16_sum(tp[kk].y) - tp[kk].y);
            hr[kk] += xj[7] * (xor32_sum(tp[kk].x) - tp[kk].x);
            hi[kk] += xj[7] * (xor32_sum(tp[kk].y) - tp[kk].y);
#endif
        }
        // remaining high bits: swizzled LDS neighbors (2x b128 each)
#pragma unroll
        for (int j = JLDS_START; j < QN; ++j) {
            const int gx = g0 ^ (1 << j);
            const int hx = h0 ^ (1 << (j - 4));
            const float4* p = (const float4*)(cur + gx + 2 * hx);
            const float4 a = p[0];
            const float4 b = p[1];
            hr[0] += xj[j] * a.x; hi[0] += xj[j] * a.y;
            hr[1] += xj[j] * a.z; hi[1] += xj[j] * a.w;
            hr[2] += xj[j] * b.x; hi[2] += xj[j] * b.y;
            hr[3] += xj[j] * b.z; hi[3] += xj[j] * b.w;
        }

        // T_k = f * Hv - T_{k-2}   (f = 1/s for k==1, else 2/s)
        const float f = (k == 1) ? inv_s : 2.0f * inv_s;
        float2 tn[4];
#pragma unroll
        for (int kk = 0; kk < 4; ++kk) {
            tn[kk] = make_float2(f * hr[kk] - tpp[kk].x, f * hi[kk] - tpp[kk].y);
        }

        // acc += c_k * T_k,  c_k = 2 Jk * (-i)^k
        const float Jk2 = 2.0f * Jc[k];
        float cr = 0.f, ci = 0.f;
        switch (k & 3) {
            case 0: cr =  Jk2; break;
            case 1: ci = -Jk2; break;
            case 2: cr = -Jk2; break;
            case 3: ci =  Jk2; break;
        }
#pragma unroll
        for (int kk = 0; kk < 4; ++kk) {
            acc[kk].x += cr * tn[kk].x - ci * tn[kk].y;
            acc[kk].y += cr * tn[kk].y + ci * tn[kk].x;
        }

        // stage T_k for next iteration's neighbor reads
        float4* w = (float4*)(nxt + l0);
        w[0] = make_float4(tn[0].x, tn[0].y, tn[1].x, tn[1].y);
        w[1] = make_float4(tn[2].x, tn[2].y, tn[3].x, tn[3].y);
        __syncthreads();

#pragma unroll
        for (int kk = 0; kk < 4; ++kk) { tpp[kk] = tp[kk]; tp[kk] = tn[kk]; }
        float2* tmp = cur; cur = nxt; nxt = tmp;
    }

    float4* o = (float4*)(psi_out + tI * QDIM + g0);
    o[0] = make_float4(acc[0].x, acc[0].y, acc[1].x, acc[1].y);
    o[1] = make_float4(acc[2].x, acc[2].y, acc[3].x, acc[3].y);
}

// Stage 2: one block per (t, b). Apply the 12 single-qubit basis rotations in
// LDS (gate for pauli index i acts on bit position QN-1-i), then gather probs.
__global__ __launch_bounds__(512) void measure_kernel(
    const float2* __restrict__ psi,
    const int* __restrict__ pauli_obs,
    const int* __restrict__ indices,
    float* __restrict__ out)
{
    __shared__ float2 st[QDIM];
    const int blk = blockIdx.x;
    const int tI = blk >> 5;
    const int b  = blk & 31;

    const float4* src = (const float4*)(psi + tI * QDIM);
    float4* dst = (float4*)st;
    for (int i = threadIdx.x; i < QDIM / 2; i += 512) dst[i] = src[i];
    __syncthreads();

    const float s = 0.70710678118654752440f;
    for (int q = 0; q < QN; ++q) {
        const int p = pauli_obs[b * QN + (QN - 1 - q)];   // gate acting on bit q
        if (p == 2) continue;                              // Z basis: identity
        const int mask = 1 << q;
        for (int it = threadIdx.x; it < QDIM / 2; it += 512) {
            const int gl = ((it & ~(mask - 1)) << 1) | (it & (mask - 1));
            const int gh = gl | mask;
            const float2 a  = st[gl];
            const float2 c2 = st[gh];
            float2 r0, r1;
            if (p == 0) {
                r0 = make_float2(s * (a.x + c2.x), s * (a.y + c2.y));
                r1 = make_float2(s * (a.x - c2.x), s * (a.y - c2.y));
            } else {
                r0 = make_float2(s * (a.x + c2.y), s * (a.y - c2.x));
                r1 = make_float2(s * (a.x - c2.y), s * (a.y + c2.x));
            }
            st[gl] = r0;
            st[gh] = r1;
        }
        __syncthreads();
    }

    if (threadIdx.x < 256) {
        const int oi = (tI * 32 + b) * 256 + threadIdx.x;
        const int idx = indices[oi];
        const float2 v = st[idx];
        out[oi] = v.x * v.x + v.y * v.y;
    }
}

extern "C" void kernel_launch(void* const* d_in, const int* in_sizes, int n_in,
                              void* d_out, int out_size, void* d_ws, size_t ws_size,
                              hipStream_t stream) {
    const int*   init_state = (const int*)d_in[0];
    const float* ts         = (const float*)d_in[1];
    const int*   pauli_obs  = (const int*)d_in[2];
    const int*   indices    = (const int*)d_in[3];
    const float* params_x   = (const float*)d_in[4];
    const float* params_zz  = (const float*)d_in[5];
    float*  out = (float*)d_out;
    float2* psi = (float2*)d_ws;   // 8 * 4096 * 8 B = 256 KB scratch

    hipLaunchKernelGGL(evolve_kernel, dim3(8), dim3(1024), 0, stream,
                       init_state, ts, params_x, params_zz, psi);
    hipLaunchKernelGGL(measure_kernel, dim3(8 * 32), dim3(512), 0, stream,
                       psi, pauli_obs, indices, out);
}

// Round 9
// 120.175 us; speedup vs baseline: 1.2566x; 1.2566x over previous
//
#include <hip/hip_runtime.h>
#include <math.h>

#define QN 12
#define QDIM 4096
#define CHEB_TOL 2e-3f
// Swizzled LDS index (float2 units): pad 2 float2 per 16 elements.
// L(g) = g + 2*(g>>4). 16-element run stays contiguous & 16B-aligned.
#define LSZ (QDIM + 2 * (QDIM / 16))

// DPP lane permutations on the VALU pipe. All involutions; HW-verified R4-R8.
// (permlane16/32_swap — asm AND builtin — causes scratch spills: dead path.)
template <int CTRL>
__device__ __forceinline__ float dppf(float x) {
    int v = __builtin_amdgcn_update_dpp(0, __float_as_int(x), CTRL, 0xF, 0xF, false);
    return __int_as_float(v);
}
#define DPP_QX1 0xB1   // quad_perm [1,0,3,2]  : lane ^ 1
#define DPP_QX2 0x4E   // quad_perm [2,3,0,1]  : lane ^ 2
#define DPP_QX3 0x1B   // quad_perm [3,2,1,0]  : lane ^ 3
#define DPP_HM  0x141  // row_half_mirror      : lane ^ 7
#define DPP_R8  0x128  // row_ror:8            : lane ^ 8
__device__ __forceinline__ float dpp_x1(float x) { return dppf<DPP_QX1>(x); }
__device__ __forceinline__ float dpp_x2(float x) { return dppf<DPP_QX2>(x); }
__device__ __forceinline__ float dpp_x4(float x) { return dppf<DPP_HM>(dppf<DPP_QX3>(x)); }
__device__ __forceinline__ float dpp_x8(float x) { return dppf<DPP_R8>(x); }

// One Chebyshev step: T_k = f*H*T1 - T2, written IN PLACE into T2 (register
// ping-pong, no copies). acc += (-i)^k * 2*J_k * T_k.
// Element bits 0..3: register; 4..7: DPP (lane xor 1,2,4,8); 8..11: LDS.
#define CHEB_STEP(T1, T2, CURB, NXTB, KVAL, FVAL, ODD)                        \
    {                                                                          \
        const int   k_ = (KVAL);                                               \
        const float f_ = (FVAL);                                               \
        float hr[16], hi[16];                                                  \
        _Pragma("unroll")                                                      \
        for (int e = 0; e < 16; ++e) {                                         \
            hr[e] = dg[e] * T1[e].x + xj[0] * T1[e ^ 1].x                      \
                  + xj[1] * T1[e ^ 2].x + xj[2] * T1[e ^ 4].x                  \
                  + xj[3] * T1[e ^ 8].x;                                       \
            hi[e] = dg[e] * T1[e].y + xj[0] * T1[e ^ 1].y                      \
                  + xj[1] * T1[e ^ 2].y + xj[2] * T1[e ^ 4].y                  \
                  + xj[3] * T1[e ^ 8].y;                                       \
            hr[e] += xj[4] * dpp_x1(T1[e].x);  hi[e] += xj[4] * dpp_x1(T1[e].y); \
            hr[e] += xj[5] * dpp_x2(T1[e].x);  hi[e] += xj[5] * dpp_x2(T1[e].y); \
            hr[e] += xj[6] * dpp_x4(T1[e].x);  hi[e] += xj[6] * dpp_x4(T1[e].y); \
            hr[e] += xj[7] * dpp_x8(T1[e].x);  hi[e] += xj[7] * dpp_x8(T1[e].y); \
        }                                                                      \
        _Pragma("unroll")                                                      \
        for (int j = 8; j < QN; ++j) {                                         \
            const int gx = g0 ^ (1 << j);                                      \
            const int hx = tid ^ (1 << (j - 4));                               \
            const float4* q4 = (const float4*)((CURB) + gx + 2 * hx);          \
            float4 nbv[8];                                                     \
            _Pragma("unroll")                                                  \
            for (int m = 0; m < 8; ++m) nbv[m] = q4[m];                        \
            _Pragma("unroll")                                                  \
            for (int m = 0; m < 8; ++m) {                                      \
                hr[2 * m]     += xj[j] * nbv[m].x;                             \
                hi[2 * m]     += xj[j] * nbv[m].y;                             \
                hr[2 * m + 1] += xj[j] * nbv[m].z;                             \
                hi[2 * m + 1] += xj[j] * nbv[m].w;                             \
            }                                                                  \
        }                                                                      \
        const float Jk2 = 2.0f * Jc[k_];                                       \
        const float c_  = (k_ & 2) ? Jk2 : -Jk2;                               \
        _Pragma("unroll")                                                      \
        for (int e = 0; e < 16; ++e) {                                         \
            const float tnx = f_ * hr[e] - T2[e].x;                            \
            const float tny = f_ * hi[e] - T2[e].y;                            \
            T2[e].x = tnx; T2[e].y = tny;                                      \
            if (ODD) {                                                         \
                acc[e].x = fmaf(-c_, tny, acc[e].x);                           \
                acc[e].y = fmaf( c_, tnx, acc[e].y);                           \
            } else {                                                           \
                acc[e].x = fmaf(-c_, tnx, acc[e].x);                           \
                acc[e].y = fmaf(-c_, tny, acc[e].y);                           \
            }                                                                  \
        }                                                                      \
        float4* w_ = (float4*)((NXTB) + l0);                                   \
        _Pragma("unroll")                                                      \
        for (int m = 0; m < 8; ++m)                                            \
            w_[m] = make_float4(T2[2 * m].x, T2[2 * m].y,                      \
                                T2[2 * m + 1].x, T2[2 * m + 1].y);             \
        __syncthreads();                                                       \
    }

// Stage 1: psi_t = exp(-i t H)|init> via Chebyshev, one block per t.
// 256 threads x 16 consecutive elements (4 waves). Only 4 LDS neighbors/iter.
__global__ __launch_bounds__(256) void evolve_kernel(
    const int* __restrict__ init_state,
    const float* __restrict__ ts,
    const float* __restrict__ params_x,
    const float* __restrict__ params_zz,
    float2* __restrict__ psi_out)
{
    __shared__ __align__(16) float2 bufA[LSZ];
    __shared__ __align__(16) float2 bufB[LSZ];
    __shared__ float  Jc[128];
    __shared__ float  suLDS[160];
    __shared__ int    dsh;

    const int tid = threadIdx.x;          // 0..255; lane = tid&63; wave = tid>>6
    const int tI  = blockIdx.x;
    const float t = ts[tI];
    const int g0 = tid * 16;              // first owned element (group h0 = tid)
    const int l0 = g0 + 2 * tid;          // swizzled float2 base = 18*tid

    if (tid < 160) suLDS[tid] = 0.f;

    float xj[QN];
    float bound = 0.f;
#pragma unroll
    for (int j = 0; j < QN; ++j) { xj[j] = params_x[j]; bound += fabsf(xj[j]); }
    float zz[QN - 1];
#pragma unroll
    for (int i = 0; i < QN - 1; ++i) { zz[i] = params_zz[i]; bound += fabsf(zz[i]); }

    // diagonal (ZZ) term for the 16 owned elements
    float dg[16];
#pragma unroll
    for (int e = 0; e < 16; ++e) {
        const int g = g0 + e;
        float dv = 0.f;
#pragma unroll
        for (int i = 0; i < QN - 1; ++i) {
            const int flip = ((g >> i) ^ (g >> (i + 1))) & 1;
            dv += zz[i] * (1.0f - 2.0f * (float)flip);
        }
        dg[e] = dv;
    }

    const float theta = t * bound;
    int dmax = (int)ceilf(theta + 5.0f * cbrtf(theta)) + 6;
    if (dmax < 8) dmax = 8;
    if (dmax > 126) dmax = 126;

    // Bessel J_k(theta) via Miller backward recurrence (fp64, rolling).
    // Thread k (<=126 < 256) captures J_k and suffix sum_{j>=k}|J_j|.
    {
        const int M = dmax + 24;
        const double th = (double)fmaxf(theta, 1e-6f);
        const double invth = 1.0 / th;
        double jkp1 = 0.0, jk = 1e-30, mine = 0.0, nrm = 0.0, suf = 0.0, su_own = 0.0;
        for (int k = M; k >= 0; --k) {
            suf += fabs(jk);
            if (k == tid) { mine = jk; su_own = suf; }
            if (k == 0) nrm += jk;
            else if ((k & 1) == 0) nrm += 2.0 * jk;
            const double jkm1 = (2.0 * (double)k * invth) * jk - jkp1;
            jkp1 = jk; jk = jkm1;
            if (fabs(jk) > 1e250) {
                jk *= 1e-250; jkp1 *= 1e-250; mine *= 1e-250;
                nrm *= 1e-250; suf *= 1e-250; su_own *= 1e-250;
            }
        }
        const double anrm = fabs(nrm);
        if (tid <= dmax) Jc[tid] = (float)(mine / nrm);
        if (tid < 160) suLDS[tid] = (float)(su_own / anrm);
    }

    const int is = init_state[0];
    const float inv_s = 1.0f / bound;

    float2 ta[16];   // ping-pong register state (T_{k-1})
    float2 tb[16];   // ping-pong register state (T_{k-2} -> T_k in place)
    float2 acc[16];
#pragma unroll
    for (int e = 0; e < 16; ++e) {
        const float v = (g0 + e == is) ? 1.0f : 0.0f;
        ta[e] = make_float2(v, 0.f);
        tb[e] = make_float2(0.f, 0.f);
    }
    {
        float4* w0 = (float4*)(bufA + l0);
#pragma unroll
        for (int m = 0; m < 8; ++m)
            w0[m] = make_float4(ta[2 * m].x, ta[2 * m].y,
                                ta[2 * m + 1].x, ta[2 * m + 1].y);
    }
    __syncthreads();   // Jc/suLDS/bufA visible

    // adaptive degree: smallest d with suffix(d+1) < tol (wave-0 double ballot)
    if (tid < 64) {
        const bool p0 = suLDS[tid + 1] < CHEB_TOL;
        const bool p1 = suLDS[tid + 65] < CHEB_TOL;
        const unsigned long long b0 = __ballot(p0);
        const unsigned long long b1 = __ballot(p1);
        if (tid == 0) {
            int dd;
            if (b0) dd = __ffsll(b0) - 1;
            else if (b1) dd = 64 + __ffsll(b1) - 1;
            else dd = dmax;
            if (dd < 2) dd = 2;
            if (dd > dmax) dd = dmax;
            dsh = dd;
        }
    }
    __syncthreads();
    const int d = dsh;

#pragma unroll
    for (int e = 0; e < 16; ++e) acc[e] = make_float2(Jc[0] * ta[e].x, 0.f);

    // k=1 (f = 1/s), then pairs (even, odd) with in-place register ping-pong.
    CHEB_STEP(ta, tb, bufA, bufB, 1, inv_s, true);
    const float f2 = 2.0f * inv_s;
    int k = 2;
    for (; k + 1 <= d; k += 2) {
        CHEB_STEP(tb, ta, bufB, bufA, k,     f2, false);
        CHEB_STEP(ta, tb, bufA, bufB, k + 1, f2, true);
    }
    if (k <= d) {
        CHEB_STEP(tb, ta, bufB, bufA, k, f2, false);
    }

    float4* o = (float4*)(psi_out + tI * QDIM + g0);
#pragma unroll
    for (int m = 0; m < 8; ++m)
        o[m] = make_float4(acc[2 * m].x, acc[2 * m].y,
                           acc[2 * m + 1].x, acc[2 * m + 1].y);
}

// Stage 2: one block per (t, b). Apply the 12 single-qubit basis rotations in
// LDS (gate for pauli index i acts on bit position QN-1-i), then gather probs.
__global__ __launch_bounds__(512) void measure_kernel(
    const float2* __restrict__ psi,
    const int* __restrict__ pauli_obs,
    const int* __restrict__ indices,
    float* __restrict__ out)
{
    __shared__ float2 st[QDIM];
    const int blk = blockIdx.x;
    const int tI = blk >> 5;
    const int b  = blk & 31;

    const float4* src = (const float4*)(psi + tI * QDIM);
    float4* dst = (float4*)st;
    for (int i = threadIdx.x; i < QDIM / 2; i += 512) dst[i] = src[i];
    __syncthreads();

    const float s = 0.70710678118654752440f;
    for (int q = 0; q < QN; ++q) {
        const int p = pauli_obs[b * QN + (QN - 1 - q)];   // gate acting on bit q
        if (p == 2) continue;                              // Z basis: identity
        const int mask = 1 << q;
        for (int it = threadIdx.x; it < QDIM / 2; it += 512) {
            const int gl = ((it & ~(mask - 1)) << 1) | (it & (mask - 1));
            const int gh = gl | mask;
            const float2 a  = st[gl];
            const float2 c2 = st[gh];
            float2 r0, r1;
            if (p == 0) {
                r0 = make_float2(s * (a.x + c2.x), s * (a.y + c2.y));
                r1 = make_float2(s * (a.x - c2.x), s * (a.y - c2.y));
            } else {
                r0 = make_float2(s * (a.x + c2.y), s * (a.y - c2.x));
                r1 = make_float2(s * (a.x - c2.y), s * (a.y + c2.x));
            }
            st[gl] = r0;
            st[gh] = r1;
        }
        __syncthreads();
    }

    if (threadIdx.x < 256) {
        const int oi = (tI * 32 + b) * 256 + threadIdx.x;
        const int idx = indices[oi];
        const float2 v = st[idx];
        out[oi] = v.x * v.x + v.y * v.y;
    }
}

extern "C" void kernel_launch(void* const* d_in, const int* in_sizes, int n_in,
                              void* d_out, int out_size, void* d_ws, size_t ws_size,
                              hipStream_t stream) {
    const int*   init_state = (const int*)d_in[0];
    const float* ts         = (const float*)d_in[1];
    const int*   pauli_obs  = (const int*)d_in[2];
    const int*   indices    = (const int*)d_in[3];
    const float* params_x   = (const float*)d_in[4];
    const float* params_zz  = (const float*)d_in[5];
    float*  out = (float*)d_out;
    float2* psi = (float2*)d_ws;   // 8 * 4096 * 8 B = 256 KB scratch

    hipLaunchKernelGGL(evolve_kernel, dim3(8), dim3(256), 0, stream,
                       init_state, ts, params_x, params_zz, psi);
    hipLaunchKernelGGL(measure_kernel, dim3(8 * 32), dim3(512), 0, stream,
                       psi, pauli_obs, indices, out);
}

// Round 10
// 116.081 us; speedup vs baseline: 1.3009x; 1.0353x over previous
//
#include <hip/hip_runtime.h>
#include <math.h>

#define QN 12
#define QDIM 4096
#define CHEB_TOL 2e-3f
// Swizzled LDS index (float2 units): pad 2 float2 per 16 elements.
// L(g) = g + 2*(g>>4). Verified R9: zero bank conflicts.
#define LSZ (QDIM + 2 * (QDIM / 16))

// DPP lane permutations on the VALU pipe. All involutions; HW-verified R4-R9.
// (permlane16/32_swap — asm AND builtin — causes scratch spills: dead path.)
template <int CTRL>
__device__ __forceinline__ float dppf(float x) {
    int v = __builtin_amdgcn_update_dpp(0, __float_as_int(x), CTRL, 0xF, 0xF, false);
    return __int_as_float(v);
}
#define DPP_QX1 0xB1   // quad_perm [1,0,3,2]  : lane ^ 1
#define DPP_QX2 0x4E   // quad_perm [2,3,0,1]  : lane ^ 2
#define DPP_QX3 0x1B   // quad_perm [3,2,1,0]  : lane ^ 3
#define DPP_HM  0x141  // row_half_mirror      : lane ^ 7
#define DPP_R8  0x128  // row_ror:8            : lane ^ 8
__device__ __forceinline__ float dpp_x1(float x) { return dppf<DPP_QX1>(x); }
__device__ __forceinline__ float dpp_x2(float x) { return dppf<DPP_QX2>(x); }
__device__ __forceinline__ float dpp_x4(float x) { return dppf<DPP_HM>(dppf<DPP_QX3>(x)); }
__device__ __forceinline__ float dpp_x8(float x) { return dppf<DPP_R8>(x); }

// One Chebyshev step: T_k = f*H*T1 - T2, written IN PLACE into T2 (register
// ping-pong). acc += (-i)^k * 2*J_k * T_k.  8 elem/thread.
// Element bits 0..2: register; 3..6: DPP (lane xor 1,2,4,8); 7..11: LDS.
// SCHEDULING: all 20 neighbor b128 loads issued FIRST, so their ~120-cyc
// latency hides under the register/DPP FMA block.
#define CHEB_STEP(T1, T2, CURB, NXTB, KVAL, FVAL, ODD)                        \
    {                                                                          \
        const int   k_ = (KVAL);                                               \
        const float f_ = (FVAL);                                               \
        float4 nbv[5][4];                                                      \
        _Pragma("unroll")                                                      \
        for (int j = 7; j < QN; ++j) {                                         \
            const int gx = g0 ^ (1 << j);                                      \
            const int hx = h0 ^ (1 << (j - 4));                                \
            const float4* q4 = (const float4*)((CURB) + gx + 2 * hx);          \
            _Pragma("unroll")                                                  \
            for (int m = 0; m < 4; ++m) nbv[j - 7][m] = q4[m];                 \
        }                                                                      \
        float hr[8], hi[8];                                                    \
        _Pragma("unroll")                                                      \
        for (int e = 0; e < 8; ++e) {                                          \
            hr[e] = dg[e] * T1[e].x + xj[0] * T1[e ^ 1].x                      \
                  + xj[1] * T1[e ^ 2].x + xj[2] * T1[e ^ 4].x;                 \
            hi[e] = dg[e] * T1[e].y + xj[0] * T1[e ^ 1].y                      \
                  + xj[1] * T1[e ^ 2].y + xj[2] * T1[e ^ 4].y;                 \
            hr[e] += xj[3] * dpp_x1(T1[e].x);  hi[e] += xj[3] * dpp_x1(T1[e].y); \
            hr[e] += xj[4] * dpp_x2(T1[e].x);  hi[e] += xj[4] * dpp_x2(T1[e].y); \
            hr[e] += xj[5] * dpp_x4(T1[e].x);  hi[e] += xj[5] * dpp_x4(T1[e].y); \
            hr[e] += xj[6] * dpp_x8(T1[e].x);  hi[e] += xj[6] * dpp_x8(T1[e].y); \
        }                                                                      \
        _Pragma("unroll")                                                      \
        for (int j = 7; j < QN; ++j) {                                         \
            _Pragma("unroll")                                                  \
            for (int m = 0; m < 4; ++m) {                                      \
                hr[2 * m]     += xj[j] * nbv[j - 7][m].x;                      \
                hi[2 * m]     += xj[j] * nbv[j - 7][m].y;                      \
                hr[2 * m + 1] += xj[j] * nbv[j - 7][m].z;                      \
                hi[2 * m + 1] += xj[j] * nbv[j - 7][m].w;                      \
            }                                                                  \
        }                                                                      \
        const float Jk2 = 2.0f * Jc[k_];                                       \
        const float c_  = (k_ & 2) ? Jk2 : -Jk2;                               \
        _Pragma("unroll")                                                      \
        for (int e = 0; e < 8; ++e) {                                          \
            const float tnx = f_ * hr[e] - T2[e].x;                            \
            const float tny = f_ * hi[e] - T2[e].y;                            \
            T2[e].x = tnx; T2[e].y = tny;                                      \
            if (ODD) {                                                         \
                acc[e].x = fmaf(-c_, tny, acc[e].x);                           \
                acc[e].y = fmaf( c_, tnx, acc[e].y);                           \
            } else {                                                           \
                acc[e].x = fmaf(-c_, tnx, acc[e].x);                           \
                acc[e].y = fmaf(-c_, tny, acc[e].y);                           \
            }                                                                  \
        }                                                                      \
        float4* w_ = (float4*)((NXTB) + l0);                                   \
        _Pragma("unroll")                                                      \
        for (int m = 0; m < 4; ++m)                                            \
            w_[m] = make_float4(T2[2 * m].x, T2[2 * m].y,                      \
                                T2[2 * m + 1].x, T2[2 * m + 1].y);             \
        __syncthreads();                                                       \
    }

// Stage 1: psi_t = exp(-i t H)|init> via Chebyshev, one block per t.
// 512 threads x 8 consecutive elements (8 waves = 2/SIMD for latency hiding).
__global__ __launch_bounds__(512) void evolve_kernel(
    const int* __restrict__ init_state,
    const float* __restrict__ ts,
    const float* __restrict__ params_x,
    const float* __restrict__ params_zz,
    float2* __restrict__ psi_out)
{
    __shared__ __align__(16) float2 bufA[LSZ];
    __shared__ __align__(16) float2 bufB[LSZ];
    __shared__ float  Jc[128];
    __shared__ float  suLDS[160];
    __shared__ int    dsh;

    const int tid = threadIdx.x;          // 0..511
    const int tI  = blockIdx.x;
    const float t = ts[tI];
    const int g0 = tid * 8;               // first owned element
    const int h0 = g0 >> 4;               // = tid >> 1
    const int l0 = g0 + 2 * h0;           // swizzled float2 base (even)

    if (tid < 160) suLDS[tid] = 0.f;

    float xj[QN];
    float bound = 0.f;
#pragma unroll
    for (int j = 0; j < QN; ++j) { xj[j] = params_x[j]; bound += fabsf(xj[j]); }
    float zz[QN - 1];
#pragma unroll
    for (int i = 0; i < QN - 1; ++i) { zz[i] = params_zz[i]; bound += fabsf(zz[i]); }

    // diagonal (ZZ) term for the 8 owned elements
    float dg[8];
#pragma unroll
    for (int e = 0; e < 8; ++e) {
        const int g = g0 + e;
        float dv = 0.f;
#pragma unroll
        for (int i = 0; i < QN - 1; ++i) {
            const int flip = ((g >> i) ^ (g >> (i + 1))) & 1;
            dv += zz[i] * (1.0f - 2.0f * (float)flip);
        }
        dg[e] = dv;
    }

    const float theta = t * bound;
    int dmax = (int)ceilf(theta + 5.0f * cbrtf(theta)) + 6;
    if (dmax < 8) dmax = 8;
    if (dmax > 126) dmax = 126;

    // Bessel J_k(theta) via Miller backward recurrence (fp64, rolling).
    {
        const int M = dmax + 24;
        const double th = (double)fmaxf(theta, 1e-6f);
        const double invth = 1.0 / th;
        double jkp1 = 0.0, jk = 1e-30, mine = 0.0, nrm = 0.0, suf = 0.0, su_own = 0.0;
        for (int k = M; k >= 0; --k) {
            suf += fabs(jk);
            if (k == tid) { mine = jk; su_own = suf; }
            if (k == 0) nrm += jk;
            else if ((k & 1) == 0) nrm += 2.0 * jk;
            const double jkm1 = (2.0 * (double)k * invth) * jk - jkp1;
            jkp1 = jk; jk = jkm1;
            if (fabs(jk) > 1e250) {
                jk *= 1e-250; jkp1 *= 1e-250; mine *= 1e-250;
                nrm *= 1e-250; suf *= 1e-250; su_own *= 1e-250;
            }
        }
        const double anrm = fabs(nrm);
        if (tid <= dmax) Jc[tid] = (float)(mine / nrm);
        if (tid < 160) suLDS[tid] = (float)(su_own / anrm);
    }

    const int is = init_state[0];
    const float inv_s = 1.0f / bound;

    float2 ta[8];    // T_{k-1}
    float2 tb[8];    // T_{k-2} -> T_k in place
    float2 acc[8];
#pragma unroll
    for (int e = 0; e < 8; ++e) {
        const float v = (g0 + e == is) ? 1.0f : 0.0f;
        ta[e] = make_float2(v, 0.f);
        tb[e] = make_float2(0.f, 0.f);
    }
    {
        float4* w0 = (float4*)(bufA + l0);
#pragma unroll
        for (int m = 0; m < 4; ++m)
            w0[m] = make_float4(ta[2 * m].x, ta[2 * m].y,
                                ta[2 * m + 1].x, ta[2 * m + 1].y);
    }
    __syncthreads();   // Jc/suLDS/bufA visible

    // adaptive degree: smallest d with suffix(d+1) < tol (wave-0 double ballot)
    if (tid < 64) {
        const bool p0 = suLDS[tid + 1] < CHEB_TOL;
        const bool p1 = suLDS[tid + 65] < CHEB_TOL;
        const unsigned long long b0 = __ballot(p0);
        const unsigned long long b1 = __ballot(p1);
        if (tid == 0) {
            int dd;
            if (b0) dd = __ffsll(b0) - 1;
            else if (b1) dd = 64 + __ffsll(b1) - 1;
            else dd = dmax;
            if (dd < 2) dd = 2;
            if (dd > dmax) dd = dmax;
            dsh = dd;
        }
    }
    __syncthreads();
    const int d = dsh;

#pragma unroll
    for (int e = 0; e < 8; ++e) acc[e] = make_float2(Jc[0] * ta[e].x, 0.f);

    // k=1 (f = 1/s), then pairs with in-place register ping-pong.
    CHEB_STEP(ta, tb, bufA, bufB, 1, inv_s, true);
    const float f2 = 2.0f * inv_s;
    int k = 2;
    for (; k + 1 <= d; k += 2) {
        CHEB_STEP(tb, ta, bufB, bufA, k,     f2, false);
        CHEB_STEP(ta, tb, bufA, bufB, k + 1, f2, true);
    }
    if (k <= d) {
        CHEB_STEP(tb, ta, bufB, bufA, k, f2, false);
    }

    float4* o = (float4*)(psi_out + tI * QDIM + g0);
#pragma unroll
    for (int m = 0; m < 4; ++m)
        o[m] = make_float4(acc[2 * m].x, acc[2 * m].y,
                           acc[2 * m + 1].x, acc[2 * m + 1].y);
}

// Stage 2: one block per (t, b). Apply the 12 single-qubit basis rotations in
// LDS (gate for pauli index i acts on bit position QN-1-i), then gather probs.
__global__ __launch_bounds__(512) void measure_kernel(
    const float2* __restrict__ psi,
    const int* __restrict__ pauli_obs,
    const int* __restrict__ indices,
    float* __restrict__ out)
{
    __shared__ float2 st[QDIM];
    const int blk = blockIdx.x;
    const int tI = blk >> 5;
    const int b  = blk & 31;

    const float4* src = (const float4*)(psi + tI * QDIM);
    float4* dst = (float4*)st;
    for (int i = threadIdx.x; i < QDIM / 2; i += 512) dst[i] = src[i];
    __syncthreads();

    const float s = 0.70710678118654752440f;
    for (int q = 0; q < QN; ++q) {
        const int p = pauli_obs[b * QN + (QN - 1 - q)];   // gate acting on bit q
        if (p == 2) continue;                              // Z basis: identity
        const int mask = 1 << q;
        for (int it = threadIdx.x; it < QDIM / 2; it += 512) {
            const int gl = ((it & ~(mask - 1)) << 1) | (it & (mask - 1));
            const int gh = gl | mask;
            const float2 a  = st[gl];
            const float2 c2 = st[gh];
            float2 r0, r1;
            if (p == 0) {
                r0 = make_float2(s * (a.x + c2.x), s * (a.y + c2.y));
                r1 = make_float2(s * (a.x - c2.x), s * (a.y - c2.y));
            } else {
                r0 = make_float2(s * (a.x + c2.y), s * (a.y - c2.x));
                r1 = make_float2(s * (a.x - c2.y), s * (a.y + c2.x));
            }
            st[gl] = r0;
            st[gh] = r1;
        }
        __syncthreads();
    }

    if (threadIdx.x < 256) {
        const int oi = (tI * 32 + b) * 256 + threadIdx.x;
        const int idx = indices[oi];
        const float2 v = st[idx];
        out[oi] = v.x * v.x + v.y * v.y;
    }
}

extern "C" void kernel_launch(void* const* d_in, const int* in_sizes, int n_in,
                              void* d_out, int out_size, void* d_ws, size_t ws_size,
                              hipStream_t stream) {
    const int*   init_state = (const int*)d_in[0];
    const float* ts         = (const float*)d_in[1];
    const int*   pauli_obs  = (const int*)d_in[2];
    const int*   indices    = (const int*)d_in[3];
    const float* params_x   = (const float*)d_in[4];
    const float* params_zz  = (const float*)d_in[5];
    float*  out = (float*)d_out;
    float2* psi = (float2*)d_ws;   // 8 * 4096 * 8 B = 256 KB scratch

    hipLaunchKernelGGL(evolve_kernel, dim3(8), dim3(512), 0, stream,
                       init_state, ts, params_x, params_zz, psi);
    hipLaunchKernelGGL(measure_kernel, dim3(8 * 32), dim3(512), 0, stream,
                       psi, pauli_obs, indices, out);
}